// Round 15
// baseline (274.362 us; speedup 1.0000x reference)
//
#include <hip/hip_runtime.h>
#include <hip/hip_bf16.h>
#include <stdint.h>

// Problem: b=32, s=256, h=1024, 5 options.
// out = 0.5 * sum_n V_n @ o_n,  V_n = sum_{i!=n} softmax_k(q_i . o_k)_n,  q_i = o_i @ W
// bias is softmax-shift-invariant -> ignored.
// Round 15: both MFMA kernels pinned at ~108us across 5 structures; shared
// invariant = gload_lds chunk service (~0.6 x 16B/cyc/CU). Switch staging to
// T14 async reg-staging (global->VGPR early, vmcnt(0)+ds_write late, swizzle
// on the write address). 2 LDS buffers each; read paths unchanged.

#define BB 32
#define SS 256
#define HH 1024

typedef __attribute__((ext_vector_type(4))) float f32x4;
typedef __attribute__((ext_vector_type(8))) __bf16 bf16x8;
typedef __attribute__((ext_vector_type(4))) __bf16 bf16x4;

__device__ constexpr int PAIR(int i, int n) { return i * 4 + (n > i ? n - 1 : n); }

__global__ void canary(float* out, float v) { out[0] = v; }

// ---------------------------------------------------------------------------
// fp32 -> bf16 flat cast of the 5 options into Obf[m][b][s][h].
__global__ __launch_bounds__(256) void cast_all(
    const float* p0, const float* p1, const float* p2, const float* p3, const float* p4,
    __bf16* __restrict__ dst)
{
  int m = blockIdx.x >> 12;
  long off = ((long)(blockIdx.x & 4095) * 256 + threadIdx.x) * 8;
  const float* src = m == 0 ? p0 : m == 1 ? p1 : m == 2 ? p2 : m == 3 ? p3 : p4;
  float4 v0 = *(const float4*)(src + off);
  float4 v1 = *(const float4*)(src + off + 4);
  bf16x8 h;
  h[0] = (__bf16)v0.x; h[1] = (__bf16)v0.y; h[2] = (__bf16)v0.z; h[3] = (__bf16)v0.w;
  h[4] = (__bf16)v1.x; h[5] = (__bf16)v1.y; h[6] = (__bf16)v1.z; h[7] = (__bf16)v1.w;
  *(bf16x8*)(dst + (long)m * BB * SS * HH + off) = h;
}

// ---------------------------------------------------------------------------
// W (1024x1024 fp32) -> Wt (bf16, transposed). 64x64 tiles, grid 256.
__global__ __launch_bounds__(256) void cast_trW(const float* __restrict__ src,
                                                __bf16* __restrict__ dstT)
{
  __shared__ __bf16 tile[64][72];
  int ct = blockIdx.x & 15, rt = blockIdx.x >> 4;
  const float* s = src + (long)(rt * 64) * 1024 + ct * 64;
  int t = threadIdx.x;
#pragma unroll
  for (int p = 0; p < 4; p++) {
    int c = t + p * 256;
    int row = c >> 4, c4 = c & 15;
    float4 v = *(const float4*)(s + (long)row * 1024 + c4 * 4);
    bf16x4 h;
    h[0] = (__bf16)v.x; h[1] = (__bf16)v.y; h[2] = (__bf16)v.z; h[3] = (__bf16)v.w;
    *(bf16x4*)&tile[row][c4 * 4] = h;
  }
  __syncthreads();
#pragma unroll
  for (int p = 0; p < 4; p++) {
    int c = t + p * 256;
    int hr = c >> 4, s4 = c & 15;
    bf16x4 h;
    h[0] = tile[s4 * 4 + 0][hr];
    h[1] = tile[s4 * 4 + 1][hr];
    h[2] = tile[s4 * 4 + 2][hr];
    h[3] = tile[s4 * 4 + 3][hr];
    *(bf16x4*)(dstT + (long)(ct * 64 + hr) * 1024 + rt * 64 + s4 * 4) = h;
  }
}

// ---------------------------------------------------------------------------
// qgemm256 v3: Q = Obf @ Wt. 256x256 tile, 512 thr, 8 waves (2x4), BK=64,
// 2x64KB dbuf. Reg-staged: loads(t+2) issued at end of tile t; at tile end
// vmcnt(0) -> ds_write(next buf, swizzled addr) -> lgkm0 -> barrier.
__global__ __launch_bounds__(512, 2) void qgemm256(
    const __bf16* __restrict__ A, const __bf16* __restrict__ Bt, __bf16* __restrict__ C)
{
  __shared__ __align__(16) char ldsb[2 * 65536];  // per buf: A[32K] B[32K]
  int lin = blockIdx.x;
  int xcd = lin & 7, idx = lin >> 3;         // 640 = 8 x 80 (bijective)
  int rt = xcd * 20 + (idx >> 2), ct = idx & 3;
  int t = threadIdx.x, l = t & 63, w = t >> 6;
  int wr = w >> 2, wc = w & 3;               // wave patch: 128 x 64
  f32x4 acc[8][4] = {};

  // staging: thread t owns chunks c = t + 512*(p&3); p<4 A, else B.
  // global source natural slot; LDS write addr swizzled: slot^(row&7).
  const char* gp[8];
  int wdst[8];
#pragma unroll
  for (int p = 0; p < 8; p++) {
    int c = t + 512 * (p & 3);
    int row = c >> 3, slot = c & 7;
    int wb = row * 128 + ((slot ^ (row & 7)) << 4);
    if (p < 4) {
      gp[p] = (const char*)(A + (long)(rt * 256 + row) * 1024 + slot * 8);
      wdst[p] = wb;
    } else {
      gp[p] = (const char*)(Bt + (long)(ct * 256 + row) * 1024 + slot * 8);
      wdst[p] = 32768 + wb;
    }
  }
  bf16x8 sreg[8];

#define LOADS                                                     \
  {                                                               \
    _Pragma("unroll") for (int p = 0; p < 8; p++) {               \
      sreg[p] = *(const bf16x8*)gp[p];                            \
      gp[p] += 128;                                               \
    }                                                             \
  }
#define WRITES(BUF)                                               \
  {                                                               \
    char* base = ldsb + (BUF) * 65536;                            \
    _Pragma("unroll") for (int p = 0; p < 8; p++)                 \
      *(bf16x8*)(base + wdst[p]) = sreg[p];                       \
  }

  int lr = l & 15, sl = l >> 4;
  int sx0 = (sl ^ (lr & 7)) * 16;        // k-half 0
  int sx1 = ((4 | sl) ^ (lr & 7)) * 16;  // k-half 1
  int arow = (wr * 128 + lr) * 128;            // + i*2048
  int brow = 32768 + (wc * 64 + lr) * 128;     // + j*2048

#define TILE(CUR)                                                                      \
  {                                                                                    \
    const char* base = ldsb + (CUR) * 65536;                                           \
    bf16x8 bfr[4][2], af[2][2];                                                        \
    _Pragma("unroll") for (int j = 0; j < 4; j++) {                                    \
      bfr[j][0] = *(const bf16x8*)(base + brow + j * 2048 + sx0);                      \
      bfr[j][1] = *(const bf16x8*)(base + brow + j * 2048 + sx1);                      \
    }                                                                                  \
    _Pragma("unroll") for (int ph = 0; ph < 4; ph++) {                                 \
      _Pragma("unroll") for (int ii = 0; ii < 2; ii++) {                               \
        int i = ph * 2 + ii;                                                           \
        af[ii][0] = *(const bf16x8*)(base + arow + i * 2048 + sx0);                    \
        af[ii][1] = *(const bf16x8*)(base + arow + i * 2048 + sx1);                    \
      }                                                                                \
      __builtin_amdgcn_s_setprio(1);                                                   \
      _Pragma("unroll") for (int ii = 0; ii < 2; ii++)                                 \
        _Pragma("unroll") for (int j = 0; j < 4; j++) {                                \
          acc[ph * 2 + ii][j] = __builtin_amdgcn_mfma_f32_16x16x32_bf16(               \
              af[ii][0], bfr[j][0], acc[ph * 2 + ii][j], 0, 0, 0);                     \
          acc[ph * 2 + ii][j] = __builtin_amdgcn_mfma_f32_16x16x32_bf16(               \
              af[ii][1], bfr[j][1], acc[ph * 2 + ii][j], 0, 0, 0);                     \
        }                                                                              \
      __builtin_amdgcn_s_setprio(0);                                                   \
    }                                                                                  \
  }

#define BODY(CUR, T)                                              \
  {                                                               \
    TILE(CUR)                                                     \
    if ((T) < 15) {                                               \
      asm volatile("s_waitcnt vmcnt(0)" ::: "memory");            \
      WRITES((CUR) ^ 1)                                           \
      if ((T) < 14) { LOADS }                                     \
    }                                                             \
    asm volatile("s_waitcnt lgkmcnt(0)" ::: "memory");            \
    __builtin_amdgcn_s_barrier();                                 \
  }

  // prologue: tile0 -> buf0; loads(tile1) in flight
  LOADS
  asm volatile("s_waitcnt vmcnt(0)" ::: "memory");
  WRITES(0)
  LOADS
  asm volatile("s_waitcnt lgkmcnt(0)" ::: "memory");
  __builtin_amdgcn_s_barrier();

  for (int it = 0; it < 8; it++) {
    BODY(0, 2 * it)
    BODY(1, 2 * it + 1)
  }
#undef BODY
#undef TILE
#undef WRITES
#undef LOADS

#pragma unroll
  for (int i = 0; i < 8; i++) {
    long mrow = (long)rt * 256 + wr * 128 + i * 16 + (sl << 2);
#pragma unroll
    for (int j = 0; j < 4; j++) {
      int n = ct * 256 + wc * 64 + j * 16 + lr;
#pragma unroll
      for (int r = 0; r < 4; r++)
        C[(mrow + r) * 1024 + n] = (__bf16)acc[i][j][r];
    }
  }
}

// ---------------------------------------------------------------------------
// gram64 v2: 20 cross-grams + lane-local softmax -> V. 512 thr, 8 waves (4x2),
// wave 16(s1)x32(s2), block 64x64. Reg-staged T14: loads(t+2) early,
// vmcnt(0)+swizzled ds_write(buf^1)+lgkm0+barrier per step. 2x40KB bufs.
__global__ __launch_bounds__(512, 2) void gram64(
    const __bf16* __restrict__ Q, const __bf16* __restrict__ O, __bf16* __restrict__ V)
{
  __shared__ __align__(16) char ldsb[2 * 40960];  // 80 KB
  int bid = blockIdx.x;
  int xcd = bid & 7, idx = bid >> 3;   // 512 = 8 XCD x 64 (bijective)
  int b = xcd * 4 + (idx >> 4);        // 4 batches per XCD
  int rem = idx & 15;
  int s1t = rem >> 2, s2t = rem & 3;   // s1t-major within batch
  int t = threadIdx.x, l = t & 63, w = t >> 6;
  int wr = w >> 1, wc = w & 1;
  f32x4 acc[20][2] = {};               // [pair][s2-half]

  // staging: thread t, p=0..4: chunk c = t + 512p in [0,2560).
  // c<1280: Q (m=c>>8, row=(c>>2)&63, slot=c&3); else O. Natural source slot;
  // LDS write addr swizzled: slot ^ ((row>>1)&3).
  const char* gp[5];
  int wdst[5];
#pragma unroll
  for (int p = 0; p < 5; p++) {
    int c = t + 512 * p;
    int isQ = c < 1280;
    int cc = isQ ? c : c - 1280;
    int m = cc >> 8, rr = (cc >> 2) & 63, slot = cc & 3;
    long row = (long)m * (BB * SS) + (long)b * SS + (isQ ? s1t : s2t) * 64 + rr;
    gp[p] = (const char*)((isQ ? Q : O) + row * HH + slot * 8);
    wdst[p] = (isQ ? 0 : 20480) + m * 4096 + rr * 64 + ((slot ^ ((rr >> 1) & 3)) << 4);
  }
  bf16x8 sreg[5];

#define LOADS                                                     \
  {                                                               \
    _Pragma("unroll") for (int p = 0; p < 5; p++) {               \
      sreg[p] = *(const bf16x8*)gp[p];                            \
      gp[p] += 64;                                                \
    }                                                             \
  }
#define WRITES(BUF)                                               \
  {                                                               \
    char* base = ldsb + (BUF) * 40960;                            \
    _Pragma("unroll") for (int p = 0; p < 5; p++)                 \
      *(bf16x8*)(base + wdst[p]) = sreg[p];                       \
  }

  int lr = l & 15, sl = l >> 4;
  int swz = (sl ^ ((lr >> 1) & 3)) * 16;
  int qoff = (wr * 16 + lr) * 64 + swz;
  int ooff0 = 20480 + (wc * 32 + lr) * 64 + swz;
  int ooff1 = ooff0 + 1024;  // +16 rows

#define COMPUTE(BUF)                                                                   \
  {                                                                                    \
    const char* base = ldsb + (BUF) * 40960;                                           \
    bf16x8 qf[5], of[5];                                                               \
    _Pragma("unroll") for (int m = 0; m < 5; m++)                                      \
      qf[m] = *(const bf16x8*)(base + m * 4096 + qoff);                                \
    _Pragma("unroll") for (int m = 0; m < 5; m++)                                      \
      of[m] = *(const bf16x8*)(base + m * 4096 + ooff0);                               \
    __builtin_amdgcn_s_setprio(1);                                                     \
    _Pragma("unroll") for (int i = 0; i < 5; i++) {                                    \
      _Pragma("unroll") for (int n = 0; n < 5; n++) {                                  \
        if (n != i)                                                                    \
          acc[PAIR(i, n)][0] = __builtin_amdgcn_mfma_f32_16x16x32_bf16(                \
              qf[i], of[n], acc[PAIR(i, n)][0], 0, 0, 0);                              \
      }                                                                                \
    }                                                                                  \
    __builtin_amdgcn_s_setprio(0);                                                     \
    _Pragma("unroll") for (int m = 0; m < 5; m++)                                      \
      of[m] = *(const bf16x8*)(base + m * 4096 + ooff1);                               \
    __builtin_amdgcn_s_setprio(1);                                                     \
    _Pragma("unroll") for (int i = 0; i < 5; i++) {                                    \
      _Pragma("unroll") for (int n = 0; n < 5; n++) {                                  \
        if (n != i)                                                                    \
          acc[PAIR(i, n)][1] = __builtin_amdgcn_mfma_f32_16x16x32_bf16(                \
              qf[i], of[n], acc[PAIR(i, n)][1], 0, 0, 0);                              \
      }                                                                                \
    }                                                                                  \
    __builtin_amdgcn_s_setprio(0);                                                     \
  }

#define BODY(CUR, T)                                              \
  {                                                               \
    COMPUTE(CUR)                                                  \
    if ((T) < 31) {                                               \
      asm volatile("s_waitcnt vmcnt(0)" ::: "memory");            \
      WRITES((CUR) ^ 1)                                           \
      if ((T) < 30) { LOADS }                                     \
    }                                                             \
    asm volatile("s_waitcnt lgkmcnt(0)" ::: "memory");            \
    __builtin_amdgcn_s_barrier();                                 \
  }

  // prologue: step0 -> buf0; loads(step1) in flight
  LOADS
  asm volatile("s_waitcnt vmcnt(0)" ::: "memory");
  WRITES(0)
  LOADS
  asm volatile("s_waitcnt lgkmcnt(0)" ::: "memory");
  __builtin_amdgcn_s_barrier();

  for (int it = 0; it < 16; it++) {
    BODY(0, 2 * it)
    BODY(1, 2 * it + 1)
  }
#undef BODY
#undef COMPUTE
#undef WRITES
#undef LOADS

  // epilogue: lane-local softmax over 4 options; C layout: s2 = l&15 (col),
  // s1 = (l>>4)*4 + r (row).
  int s1b = s1t * 64 + wr * 16 + sl * 4;
  int s2b = s2t * 64 + wc * 32 + lr;
#pragma unroll
  for (int h = 0; h < 2; h++) {
#pragma unroll
    for (int r = 0; r < 4; r++) {
      float vacc[5] = {0.f, 0.f, 0.f, 0.f, 0.f};
#pragma unroll
      for (int i = 0; i < 5; i++) {
        float gg[5];
        float mx = -3.0e38f;
#pragma unroll
        for (int n = 0; n < 5; n++)
          if (n != i) { gg[n] = acc[PAIR(i, n)][h][r]; mx = fmaxf(mx, gg[n]); }
        float ee[5], ssum = 0.f;
#pragma unroll
        for (int n = 0; n < 5; n++)
          if (n != i) { ee[n] = __expf(gg[n] - mx); ssum += ee[n]; }
        float inv = 1.0f / ssum;
#pragma unroll
        for (int n = 0; n < 5; n++)
          if (n != i) vacc[n] += ee[n] * inv;
      }
      int s1 = s1b + r, s2 = s2b + h * 16;
#pragma unroll
      for (int n = 0; n < 5; n++)
        V[((long)(n * BB + b) * SS + s1) * SS + s2] = (__bf16)vacc[n];
    }
  }
}

// ---------------------------------------------------------------------------
// out = 0.5 * sum_n V_n @ o_n (per batch). A: V rows (bf16, s2-contig).
// B: Obf bf16 (s2 x h), transposed in LDS via 4x4 register sub-blocks.
__global__ __launch_bounds__(256) void pvgemm(
    const __bf16* __restrict__ Vb, const __bf16* __restrict__ Obf, float* __restrict__ out)
{
  __shared__ __bf16 smA[128][40];
  __shared__ __bf16 smB[128][40];
  int bid = blockIdx.x;
  int b = bid >> 4, s1t = (bid >> 3) & 1, ht = bid & 7;
  int t = threadIdx.x, l = t & 63, w = t >> 6;
  int wm = w >> 1, wn = w & 1;
  f32x4 acc[4][4] = {};
#pragma unroll
  for (int n = 0; n < 5; n++) {
    const __bf16* On = Obf + (long)n * BB * SS * HH;
    for (int st2 = 0; st2 < 8; st2++) {
      int s20 = st2 * 32;
#pragma unroll
      for (int p = 0; p < 2; p++) {
        int c = t + p * 256;
        int row = c >> 2, sl = c & 3;
        *(bf16x8*)&smA[row][sl * 8] =
            *(const bf16x8*)(Vb + (long)(n * BB + b) * SS * SS + (long)(s1t * 128 + row) * SS +
                             s20 + sl * 8);
      }
      {
        int h4 = (t & 31) * 4, s2q = (t >> 5) * 4;
        const __bf16* src = On + ((long)b * 256 + s20 + s2q) * 1024 + ht * 128 + h4;
        bf16x4 v0 = *(const bf16x4*)(src);
        bf16x4 v1 = *(const bf16x4*)(src + 1024);
        bf16x4 v2 = *(const bf16x4*)(src + 2048);
        bf16x4 v3 = *(const bf16x4*)(src + 3072);
        bf16x4 c0, c1, c2, c3;
        c0[0] = v0[0]; c0[1] = v1[0]; c0[2] = v2[0]; c0[3] = v3[0];
        c1[0] = v0[1]; c1[1] = v1[1]; c1[2] = v2[1]; c1[3] = v3[1];
        c2[0] = v0[2]; c2[1] = v1[2]; c2[2] = v2[2]; c2[3] = v3[2];
        c3[0] = v0[3]; c3[1] = v1[3]; c3[2] = v2[3]; c3[3] = v3[3];
        *(bf16x4*)&smB[h4 + 0][s2q] = c0;
        *(bf16x4*)&smB[h4 + 1][s2q] = c1;
        *(bf16x4*)&smB[h4 + 2][s2q] = c2;
        *(bf16x4*)&smB[h4 + 3][s2q] = c3;
      }
      __syncthreads();
      bf16x8 af[4], bfr[4];
      int sl = l >> 4, lr = l & 15;
#pragma unroll
      for (int i = 0; i < 4; i++) {
        af[i]  = *(const bf16x8*)&smA[wm * 64 + i * 16 + lr][sl * 8];
        bfr[i] = *(const bf16x8*)&smB[wn * 64 + i * 16 + lr][sl * 8];
      }
#pragma unroll
      for (int i = 0; i < 4; i++)
#pragma unroll
        for (int j = 0; j < 4; j++)
          acc[i][j] = __builtin_amdgcn_mfma_f32_16x16x32_bf16(af[i], bfr[j], acc[i][j], 0, 0, 0);
      __syncthreads();
    }
  }
#pragma unroll
  for (int i = 0; i < 4; i++) {
    int m = s1t * 128 + wm * 64 + i * 16 + ((l >> 4) << 2);
#pragma unroll
    for (int j = 0; j < 4; j++) {
      int n = ht * 128 + wn * 64 + j * 16 + (l & 15);
#pragma unroll
      for (int r = 0; r < 4; r++)
        out[(long)(b * SS + m + r) * HH + n] = 0.5f * acc[i][j][r];
    }
  }
}

// ---------------------------------------------------------------------------
extern "C" void kernel_launch(void* const* d_in, const int* in_sizes, int n_in,
                              void* d_out, int out_size, void* d_ws, size_t ws_size,
                              hipStream_t stream)
{
  const size_t SZ_W = (size_t)HH * HH * 2;           //  2 MB
  const size_t SZ_Q = (size_t)5 * BB * SS * HH * 2;  // 84 MB
  const size_t SZ_V = (size_t)5 * BB * SS * SS * 2;  // 21 MB
  const size_t SZ_O = (size_t)5 * BB * SS * HH * 2;  // 84 MB
  const size_t NEED = SZ_W + SZ_Q + SZ_V + SZ_O;     // 191 MB (proven available r4)
  if (ws_size < NEED) {
    canary<<<1, 1, 0, stream>>>((float*)d_out, (float)(ws_size >> 20));
    return;
  }
  char* ws = (char*)d_ws;
  __bf16* Wt  = (__bf16*)ws;
  __bf16* Qb  = (__bf16*)(ws + SZ_W);
  __bf16* Vb  = (__bf16*)(ws + SZ_W + SZ_Q);
  __bf16* Obf = (__bf16*)(ws + SZ_W + SZ_Q + SZ_V);
  const float* o0 = (const float*)d_in[0];
  const float* o1 = (const float*)d_in[1];
  const float* o2 = (const float*)d_in[2];
  const float* o3 = (const float*)d_in[3];
  const float* o4 = (const float*)d_in[4];

  cast_trW<<<256, 256, 0, stream>>>((const float*)d_in[5], Wt);
  cast_all<<<5 * 4096, 256, 0, stream>>>(o0, o1, o2, o3, o4, Obf);
  qgemm256<<<640, 512, 0, stream>>>(Obf, Wt, Qb);
  gram64<<<512, 512, 0, stream>>>(Qb, Obf, Vb);
  pvgemm<<<512, 256, 0, stream>>>(Vb, Obf, (float*)d_out);
}

// Round 16
// 269.572 us; speedup vs baseline: 1.0178x; 1.0178x over previous
//
#include <hip/hip_runtime.h>
#include <hip/hip_bf16.h>
#include <stdint.h>

// Problem: b=32, s=256, h=1024, 5 options.
// out = 0.5 * sum_n V_n @ o_n,  V_n = sum_{i!=n} softmax_k(q_i . o_k)_n,  q_i = o_i @ W
// bias is softmax-shift-invariant -> ignored.
// Round 16: qgemm rebuilt as a faithful m201 8-phase port: 4 phases/K-tile
// (mh x kh quadrants), per phase {ds_read + 1 half-tile gload -> barrier ->
// lgkm0+sched_barrier -> setprio 16xMFMA -> barrier}; K-split LDS halves so
// counted vmcnt(4) (never 0 in loop) works with 2 buffers. B-frags reg-cached
// across mh. gram64 v2 / pvgemm / casts frozen.

#define BB 32
#define SS 256
#define HH 1024

typedef __attribute__((ext_vector_type(4))) float f32x4;
typedef __attribute__((ext_vector_type(8))) __bf16 bf16x8;
typedef __attribute__((ext_vector_type(4))) __bf16 bf16x4;

__device__ constexpr int PAIR(int i, int n) { return i * 4 + (n > i ? n - 1 : n); }

__device__ __forceinline__ void gload_lds16(const void* g, void* l) {
  __builtin_amdgcn_global_load_lds((const __attribute__((address_space(1))) void*)g,
                                   (__attribute__((address_space(3))) void*)l, 16, 0, 0);
}

__global__ void canary(float* out, float v) { out[0] = v; }

// ---------------------------------------------------------------------------
// fp32 -> bf16 flat cast of the 5 options into Obf[m][b][s][h].
__global__ __launch_bounds__(256) void cast_all(
    const float* p0, const float* p1, const float* p2, const float* p3, const float* p4,
    __bf16* __restrict__ dst)
{
  int m = blockIdx.x >> 12;
  long off = ((long)(blockIdx.x & 4095) * 256 + threadIdx.x) * 8;
  const float* src = m == 0 ? p0 : m == 1 ? p1 : m == 2 ? p2 : m == 3 ? p3 : p4;
  float4 v0 = *(const float4*)(src + off);
  float4 v1 = *(const float4*)(src + off + 4);
  bf16x8 h;
  h[0] = (__bf16)v0.x; h[1] = (__bf16)v0.y; h[2] = (__bf16)v0.z; h[3] = (__bf16)v0.w;
  h[4] = (__bf16)v1.x; h[5] = (__bf16)v1.y; h[6] = (__bf16)v1.z; h[7] = (__bf16)v1.w;
  *(bf16x8*)(dst + (long)m * BB * SS * HH + off) = h;
}

// ---------------------------------------------------------------------------
// W (1024x1024 fp32) -> Wt (bf16, transposed). 64x64 tiles, grid 256.
__global__ __launch_bounds__(256) void cast_trW(const float* __restrict__ src,
                                                __bf16* __restrict__ dstT)
{
  __shared__ __bf16 tile[64][72];
  int ct = blockIdx.x & 15, rt = blockIdx.x >> 4;
  const float* s = src + (long)(rt * 64) * 1024 + ct * 64;
  int t = threadIdx.x;
#pragma unroll
  for (int p = 0; p < 4; p++) {
    int c = t + p * 256;
    int row = c >> 4, c4 = c & 15;
    float4 v = *(const float4*)(s + (long)row * 1024 + c4 * 4);
    bf16x4 h;
    h[0] = (__bf16)v.x; h[1] = (__bf16)v.y; h[2] = (__bf16)v.z; h[3] = (__bf16)v.w;
    *(bf16x4*)&tile[row][c4 * 4] = h;
  }
  __syncthreads();
#pragma unroll
  for (int p = 0; p < 4; p++) {
    int c = t + p * 256;
    int hr = c >> 4, s4 = c & 15;
    bf16x4 h;
    h[0] = tile[s4 * 4 + 0][hr];
    h[1] = tile[s4 * 4 + 1][hr];
    h[2] = tile[s4 * 4 + 2][hr];
    h[3] = tile[s4 * 4 + 3][hr];
    *(bf16x4*)(dstT + (long)(ct * 64 + hr) * 1024 + rt * 64 + s4 * 4) = h;
  }
}

// ---------------------------------------------------------------------------
// qgemm256 v4 (m201-style): 256x256 tile, 512 thr, 8 waves (2x4), BK=64.
// LDS per buf: A-k0[256][32] @0, A-k1 @16K, B-k0 @32K, B-k1 @48K (K-split
// halves). Per tile 4 phases (mh,kh); stage half-tile p of tile t+1 during
// phase p of tile t; vmcnt(4) at odd-phase closes only.
__global__ __launch_bounds__(512, 2) void qgemm256(
    const __bf16* __restrict__ A, const __bf16* __restrict__ Bt, __bf16* __restrict__ C)
{
  __shared__ __align__(16) char ldsb[2 * 65536];  // 128 KB
  int lin = blockIdx.x;
  int xcd = lin & 7, idx = lin >> 3;         // 640 = 8 x 80 (bijective)
  int rt = xcd * 20 + (idx >> 2), ct = idx & 3;
  int t = threadIdx.x, l = t & 63, w = t >> 6;
  int wr = w >> 2, wc = w & 3;               // wave patch: 128 x 64
  f32x4 acc[2][4][4] = {};                   // [mh][i][j]

  // Staging: half-tile h: 0=A-k0, 1=B-k0, 2=A-k1, 3=B-k1; 2 chunks/thread.
  // chunk c: row=c>>2, slot=c&3; source slot pre-swizzled (c&3)^((c>>3)&3);
  // LDS dest linear (wave-uniform base + HW lane*16).
  const char* gp[4][2];
  int dst[4][2];
#pragma unroll
  for (int h = 0; h < 4; h++) {
#pragma unroll
    for (int cc = 0; cc < 2; cc++) {
      int c = t + 512 * cc;
      int row = c >> 2;
      int sl2 = (c & 3) ^ ((c >> 3) & 3);
      int kh = h >> 1, isB = h & 1;
      const __bf16* src = isB ? (Bt + (long)(ct * 256 + row) * 1024)
                              : (A + (long)(rt * 256 + row) * 1024);
      gp[h][cc] = (const char*)(src + kh * 32 + sl2 * 8);
      dst[h][cc] = isB * 32768 + kh * 16384 + ((t & ~63) + 512 * cc) * 16;
    }
  }

  int lr = l & 15, sl = l >> 4;
  int swz = (sl ^ ((lr >> 1) & 3)) * 16;
  int abase = (wr * 128 + lr) * 64 + swz;           // + kh*16384 + mh*4096 + i*1024
  int bbase = 32768 + (wc * 64 + lr) * 64 + swz;    // + kh*16384 + j*1024
  bf16x8 bq[4];                                     // B frags cached across mh

#define STAGEH(H, BUF)                                                  \
  {                                                                     \
    char* sb = ldsb + (BUF) * 65536;                                    \
    gload_lds16(gp[H][0], sb + dst[H][0]);                              \
    gload_lds16(gp[H][1], sb + dst[H][1]);                              \
    gp[H][0] += 128; gp[H][1] += 128;                                   \
  }

#define PHASE(BUF, MH, KH, STH, DOSTAGE, VMODE)                                        \
  {                                                                                    \
    const char* base = ldsb + (BUF) * 65536;                                           \
    bf16x8 af[4];                                                                      \
    if ((MH) == 0) {                                                                   \
      _Pragma("unroll") for (int j = 0; j < 4; j++)                                    \
        bq[j] = *(const bf16x8*)(base + (KH) * 16384 + bbase + j * 1024);              \
    }                                                                                  \
    _Pragma("unroll") for (int i = 0; i < 4; i++)                                      \
      af[i] = *(const bf16x8*)(base + (KH) * 16384 + abase + (MH) * 4096 + i * 1024);  \
    if (DOSTAGE) { STAGEH(STH, (BUF) ^ 1) }                                            \
    __builtin_amdgcn_s_barrier();                                                      \
    asm volatile("s_waitcnt lgkmcnt(0)" ::: "memory");                                 \
    __builtin_amdgcn_sched_barrier(0);                                                 \
    __builtin_amdgcn_s_setprio(1);                                                     \
    _Pragma("unroll") for (int i = 0; i < 4; i++)                                      \
      _Pragma("unroll") for (int j = 0; j < 4; j++)                                    \
        acc[MH][i][j] = __builtin_amdgcn_mfma_f32_16x16x32_bf16(                       \
            af[i], bq[j], acc[MH][i][j], 0, 0, 0);                                     \
    __builtin_amdgcn_s_setprio(0);                                                     \
    if ((VMODE) == 4) asm volatile("s_waitcnt vmcnt(4)" ::: "memory");                 \
    if ((VMODE) == 0) asm volatile("s_waitcnt vmcnt(0)" ::: "memory");                 \
    __builtin_amdgcn_s_barrier();                                                      \
  }

  // prologue: stage tile 0 (4 halves, issue order A-k0,B-k0,A-k1,B-k1)
  STAGEH(0, 0) STAGEH(1, 0) STAGEH(2, 0) STAGEH(3, 0)
  asm volatile("s_waitcnt vmcnt(4)" ::: "memory");  // A-k0,B-k0 landed
  __builtin_amdgcn_s_barrier();

  for (int tt = 0; tt < 16; tt++) {
    int cur = tt & 1;
    int st = tt < 15;
    int vm1 = (tt == 15) ? 0 : 4;   // P1 close: need this tile's k1 halves next
    int vm3 = (tt == 15) ? -1 : 4;  // P3 close: need next tile's k0 halves
    PHASE(cur, 0, 0, 0, st, -1)
    PHASE(cur, 1, 0, 1, st, vm1)
    PHASE(cur, 0, 1, 2, st, -1)
    PHASE(cur, 1, 1, 3, st, vm3)
  }
#undef PHASE
#undef STAGEH

#pragma unroll
  for (int mh = 0; mh < 2; mh++) {
#pragma unroll
    for (int i = 0; i < 4; i++) {
      long mrow = (long)rt * 256 + wr * 128 + mh * 64 + i * 16 + sl * 4;
#pragma unroll
      for (int j = 0; j < 4; j++) {
        int n = ct * 256 + wc * 64 + j * 16 + lr;
#pragma unroll
        for (int r = 0; r < 4; r++)
          C[(mrow + r) * 1024 + n] = (__bf16)acc[mh][i][j][r];
      }
    }
  }
}

// ---------------------------------------------------------------------------
// gram64 v2: 20 cross-grams + lane-local softmax -> V. (r15, ~108us)
__global__ __launch_bounds__(512, 2) void gram64(
    const __bf16* __restrict__ Q, const __bf16* __restrict__ O, __bf16* __restrict__ V)
{
  __shared__ __align__(16) char ldsb[2 * 40960];  // 80 KB
  int bid = blockIdx.x;
  int xcd = bid & 7, idx = bid >> 3;   // 512 = 8 XCD x 64 (bijective)
  int b = xcd * 4 + (idx >> 4);        // 4 batches per XCD
  int rem = idx & 15;
  int s1t = rem >> 2, s2t = rem & 3;   // s1t-major within batch
  int t = threadIdx.x, l = t & 63, w = t >> 6;
  int wr = w >> 1, wc = w & 1;
  f32x4 acc[20][2] = {};

  const char* gp[5];
  int wdst[5];
#pragma unroll
  for (int p = 0; p < 5; p++) {
    int c = t + 512 * p;
    int isQ = c < 1280;
    int cc = isQ ? c : c - 1280;
    int m = cc >> 8, rr = (cc >> 2) & 63, slot = cc & 3;
    long row = (long)m * (BB * SS) + (long)b * SS + (isQ ? s1t : s2t) * 64 + rr;
    gp[p] = (const char*)((isQ ? Q : O) + row * HH + slot * 8);
    wdst[p] = (isQ ? 0 : 20480) + m * 4096 + rr * 64 + ((slot ^ ((rr >> 1) & 3)) << 4);
  }
  bf16x8 sreg[5];

#define LOADS                                                     \
  {                                                               \
    _Pragma("unroll") for (int p = 0; p < 5; p++) {               \
      sreg[p] = *(const bf16x8*)gp[p];                            \
      gp[p] += 64;                                                \
    }                                                             \
  }
#define WRITES(BUF)                                               \
  {                                                               \
    char* base = ldsb + (BUF) * 40960;                            \
    _Pragma("unroll") for (int p = 0; p < 5; p++)                 \
      *(bf16x8*)(base + wdst[p]) = sreg[p];                       \
  }

  int lr = l & 15, sl = l >> 4;
  int swz = (sl ^ ((lr >> 1) & 3)) * 16;
  int qoff = (wr * 16 + lr) * 64 + swz;
  int ooff0 = 20480 + (wc * 32 + lr) * 64 + swz;
  int ooff1 = ooff0 + 1024;

#define COMPUTE(BUF)                                                                   \
  {                                                                                    \
    const char* base = ldsb + (BUF) * 40960;                                           \
    bf16x8 qf[5], of[5];                                                               \
    _Pragma("unroll") for (int m = 0; m < 5; m++)                                      \
      qf[m] = *(const bf16x8*)(base + m * 4096 + qoff);                                \
    _Pragma("unroll") for (int m = 0; m < 5; m++)                                      \
      of[m] = *(const bf16x8*)(base + m * 4096 + ooff0);                               \
    __builtin_amdgcn_s_setprio(1);                                                     \
    _Pragma("unroll") for (int i = 0; i < 5; i++) {                                    \
      _Pragma("unroll") for (int n = 0; n < 5; n++) {                                  \
        if (n != i)                                                                    \
          acc[PAIR(i, n)][0] = __builtin_amdgcn_mfma_f32_16x16x32_bf16(                \
              qf[i], of[n], acc[PAIR(i, n)][0], 0, 0, 0);                              \
      }                                                                                \
    }                                                                                  \
    __builtin_amdgcn_s_setprio(0);                                                     \
    _Pragma("unroll") for (int m = 0; m < 5; m++)                                      \
      of[m] = *(const bf16x8*)(base + m * 4096 + ooff1);                               \
    __builtin_amdgcn_s_setprio(1);                                                     \
    _Pragma("unroll") for (int i = 0; i < 5; i++) {                                    \
      _Pragma("unroll") for (int n = 0; n < 5; n++) {                                  \
        if (n != i)                                                                    \
          acc[PAIR(i, n)][1] = __builtin_amdgcn_mfma_f32_16x16x32_bf16(                \
              qf[i], of[n], acc[PAIR(i, n)][1], 0, 0, 0);                              \
      }                                                                                \
    }                                                                                  \
    __builtin_amdgcn_s_setprio(0);                                                     \
  }

#define BODY(CUR, T)                                              \
  {                                                               \
    COMPUTE(CUR)                                                  \
    if ((T) < 31) {                                               \
      asm volatile("s_waitcnt vmcnt(0)" ::: "memory");            \
      WRITES((CUR) ^ 1)                                           \
      if ((T) < 30) { LOADS }                                     \
    }                                                             \
    asm volatile("s_waitcnt lgkmcnt(0)" ::: "memory");            \
    __builtin_amdgcn_s_barrier();                                 \
  }

  LOADS
  asm volatile("s_waitcnt vmcnt(0)" ::: "memory");
  WRITES(0)
  LOADS
  asm volatile("s_waitcnt lgkmcnt(0)" ::: "memory");
  __builtin_amdgcn_s_barrier();

  for (int it = 0; it < 16; it++) {
    BODY(0, 2 * it)
    BODY(1, 2 * it + 1)
  }
#undef BODY
#undef COMPUTE
#undef WRITES
#undef LOADS

  int s1b = s1t * 64 + wr * 16 + sl * 4;
  int s2b = s2t * 64 + wc * 32 + lr;
#pragma unroll
  for (int h = 0; h < 2; h++) {
#pragma unroll
    for (int r = 0; r < 4; r++) {
      float vacc[5] = {0.f, 0.f, 0.f, 0.f, 0.f};
#pragma unroll
      for (int i = 0; i < 5; i++) {
        float gg[5];
        float mx = -3.0e38f;
#pragma unroll
        for (int n = 0; n < 5; n++)
          if (n != i) { gg[n] = acc[PAIR(i, n)][h][r]; mx = fmaxf(mx, gg[n]); }
        float ee[5], ssum = 0.f;
#pragma unroll
        for (int n = 0; n < 5; n++)
          if (n != i) { ee[n] = __expf(gg[n] - mx); ssum += ee[n]; }
        float inv = 1.0f / ssum;
#pragma unroll
        for (int n = 0; n < 5; n++)
          if (n != i) vacc[n] += ee[n] * inv;
      }
      int s1 = s1b + r, s2 = s2b + h * 16;
#pragma unroll
      for (int n = 0; n < 5; n++)
        V[((long)(n * BB + b) * SS + s1) * SS + s2] = (__bf16)vacc[n];
    }
  }
}

// ---------------------------------------------------------------------------
// out = 0.5 * sum_n V_n @ o_n (per batch). A: V rows (bf16, s2-contig).
// B: Obf bf16 (s2 x h), transposed in LDS via 4x4 register sub-blocks.
__global__ __launch_bounds__(256) void pvgemm(
    const __bf16* __restrict__ Vb, const __bf16* __restrict__ Obf, float* __restrict__ out)
{
  __shared__ __bf16 smA[128][40];
  __shared__ __bf16 smB[128][40];
  int bid = blockIdx.x;
  int b = bid >> 4, s1t = (bid >> 3) & 1, ht = bid & 7;
  int t = threadIdx.x, l = t & 63, w = t >> 6;
  int wm = w >> 1, wn = w & 1;
  f32x4 acc[4][4] = {};
#pragma unroll
  for (int n = 0; n < 5; n++) {
    const __bf16* On = Obf + (long)n * BB * SS * HH;
    for (int st2 = 0; st2 < 8; st2++) {
      int s20 = st2 * 32;
#pragma unroll
      for (int p = 0; p < 2; p++) {
        int c = t + p * 256;
        int row = c >> 2, sl = c & 3;
        *(bf16x8*)&smA[row][sl * 8] =
            *(const bf16x8*)(Vb + (long)(n * BB + b) * SS * SS + (long)(s1t * 128 + row) * SS +
                             s20 + sl * 8);
      }
      {
        int h4 = (t & 31) * 4, s2q = (t >> 5) * 4;
        const __bf16* src = On + ((long)b * 256 + s20 + s2q) * 1024 + ht * 128 + h4;
        bf16x4 v0 = *(const bf16x4*)(src);
        bf16x4 v1 = *(const bf16x4*)(src + 1024);
        bf16x4 v2 = *(const bf16x4*)(src + 2048);
        bf16x4 v3 = *(const bf16x4*)(src + 3072);
        bf16x4 c0, c1, c2, c3;
        c0[0] = v0[0]; c0[1] = v1[0]; c0[2] = v2[0]; c0[3] = v3[0];
        c1[0] = v0[1]; c1[1] = v1[1]; c1[2] = v2[1]; c1[3] = v3[1];
        c2[0] = v0[2]; c2[1] = v1[2]; c2[2] = v2[2]; c2[3] = v3[2];
        c3[0] = v0[3]; c3[1] = v1[3]; c3[2] = v2[3]; c3[3] = v3[3];
        *(bf16x4*)&smB[h4 + 0][s2q] = c0;
        *(bf16x4*)&smB[h4 + 1][s2q] = c1;
        *(bf16x4*)&smB[h4 + 2][s2q] = c2;
        *(bf16x4*)&smB[h4 + 3][s2q] = c3;
      }
      __syncthreads();
      bf16x8 af[4], bfr[4];
      int sl = l >> 4, lr = l & 15;
#pragma unroll
      for (int i = 0; i < 4; i++) {
        af[i]  = *(const bf16x8*)&smA[wm * 64 + i * 16 + lr][sl * 8];
        bfr[i] = *(const bf16x8*)&smB[wn * 64 + i * 16 + lr][sl * 8];
      }
#pragma unroll
      for (int i = 0; i < 4; i++)
#pragma unroll
        for (int j = 0; j < 4; j++)
          acc[i][j] = __builtin_amdgcn_mfma_f32_16x16x32_bf16(af[i], bfr[j], acc[i][j], 0, 0, 0);
      __syncthreads();
    }
  }
#pragma unroll
  for (int i = 0; i < 4; i++) {
    int m = s1t * 128 + wm * 64 + i * 16 + ((l >> 4) << 2);
#pragma unroll
    for (int j = 0; j < 4; j++) {
      int n = ht * 128 + wn * 64 + j * 16 + (l & 15);
#pragma unroll
      for (int r = 0; r < 4; r++)
        out[(long)(b * SS + m + r) * HH + n] = 0.5f * acc[i][j][r];
    }
  }
}

// ---------------------------------------------------------------------------
extern "C" void kernel_launch(void* const* d_in, const int* in_sizes, int n_in,
                              void* d_out, int out_size, void* d_ws, size_t ws_size,
                              hipStream_t stream)
{
  const size_t SZ_W = (size_t)HH * HH * 2;           //  2 MB
  const size_t SZ_Q = (size_t)5 * BB * SS * HH * 2;  // 84 MB
  const size_t SZ_V = (size_t)5 * BB * SS * SS * 2;  // 21 MB
  const size_t SZ_O = (size_t)5 * BB * SS * HH * 2;  // 84 MB
  const size_t NEED = SZ_W + SZ_Q + SZ_V + SZ_O;     // 191 MB (proven available r4)
  if (ws_size < NEED) {
    canary<<<1, 1, 0, stream>>>((float*)d_out, (float)(ws_size >> 20));
    return;
  }
  char* ws = (char*)d_ws;
  __bf16* Wt  = (__bf16*)ws;
  __bf16* Qb  = (__bf16*)(ws + SZ_W);
  __bf16* Vb  = (__bf16*)(ws + SZ_W + SZ_Q);
  __bf16* Obf = (__bf16*)(ws + SZ_W + SZ_Q + SZ_V);
  const float* o0 = (const float*)d_in[0];
  const float* o1 = (const float*)d_in[1];
  const float* o2 = (const float*)d_in[2];
  const float* o3 = (const float*)d_in[3];
  const float* o4 = (const float*)d_in[4];

  cast_trW<<<256, 256, 0, stream>>>((const float*)d_in[5], Wt);
  cast_all<<<5 * 4096, 256, 0, stream>>>(o0, o1, o2, o3, o4, Obf);
  qgemm256<<<640, 512, 0, stream>>>(Obf, Wt, Qb);
  gram64<<<512, 512, 0, stream>>>(Qb, Obf, Vb);
  pvgemm<<<512, 256, 0, stream>>>(Vb, Obf, (float*)d_out);
}